// Round 9
// baseline (546.293 us; speedup 1.0000x reference)
//
#include <hip/hip_runtime.h>
#include <hip/hip_bf16.h>
#include <stddef.h>

#define DEVINL __device__ __forceinline__

typedef __attribute__((ext_vector_type(8))) short short8;
typedef __attribute__((ext_vector_type(4))) float f32x4;

static constexpr int S_LEN = 2048;
static constexpr int C_LEN = 2048;
static constexpr int DMODEL = 768;
static constexpr int NHEAD = 12;
static constexpr int DHEAD = 64;
static constexpr float SCALE = 0.125f;   // 1/sqrt(64)

// ---------- bf16 helpers (bit-level, RNE) ----------
DEVINL float bf2f(short s) {
    union { unsigned u; float f; } v;
    v.u = ((unsigned)(unsigned short)s) << 16;
    return v.f;
}
DEVINL short f2bf(float f) {
    union { float f; unsigned u; } v;
    v.f = f;
    unsigned r = v.u + 0x7FFFu + ((v.u >> 16) & 1u);
    return (short)(r >> 16);
}
DEVINL f32x4 zero4() { f32x4 z; z[0]=0.f; z[1]=0.f; z[2]=0.f; z[3]=0.f; return z; }

// ---------- LDS XOR swizzle: elem-index XOR, 16B-granule, breaks column bank aliasing ----------
DEVINL int swz(int width, int row, int col) {
    return (row * width + col) ^ ((row & 7) << 3);
}

// ---------- async global->LDS staging, width 16, source pre-swizzled (rule #21) ----------
DEVINL void gl_lds16(const short* g, short* l) {
    __builtin_amdgcn_global_load_lds(
        (const __attribute__((address_space(1))) void*)g,
        (__attribute__((address_space(3))) void*)l,
        16, 0, 0);
}

// stage [ROWS][WIDTH] bf16 tile: LDS linear dest, global src address carries the swizzle.
// 256 threads = 4 waves; per lane: ROWS*WIDTH/8/256 gl_lds16 calls (A64x64:2, B128x64:4, V64x128:4)
template<int ROWS, int WIDTH>
DEVINL void stage_lds_swz(short* lds_tile, const short* src, int src_stride, int w, int lane) {
    constexpr int CPR = WIDTH / 8;             // 16B chunks per row
    constexpr int CH  = ROWS * CPR;
    for (int c0 = w * 64; c0 < CH; c0 += 256) {
        int chunk = c0 + lane;
        int row   = chunk / CPR;
        int ccol  = chunk % CPR;
        int scol  = ccol ^ (row & 7);          // inverse swizzle on the source
        gl_lds16(src + (size_t)row * src_stride + scol * 8, lds_tile + c0 * 8);
    }
}

// ---------- VALU staging (for compute-during-stage), swizzled writes ----------
DEVINL void stage_addcol(short* dst, const short* src, const float* p1, const float* p2,
                         int col0, int src_stride) {
    for (int c = threadIdx.x; c < 1024; c += 256) {
        int row = c >> 3;
        int cc  = (c & 7) * 8;
        short8 a = *(const short8*)(src + (size_t)row * src_stride + cc);
        short8 r;
#pragma unroll
        for (int e = 0; e < 8; ++e)
            r[e] = f2bf(bf2f(a[e]) + (p1[col0 + cc + e] - p2[col0 + cc + e]) * SCALE);
        *(short8*)(dst + swz(64, row, cc)) = r;
    }
}

// ---------- one BK=64 MFMA step for a 128x128 tile, 4 waves in 2x2 of 64x64 ----------
DEVINL void mfma_step_128(const short* As, const short* Bs, f32x4 acc[4][4],
                          int wr, int wc, int lane) {
#pragma unroll
    for (int kk = 0; kk < 64; kk += 32) {
        short8 a[4], b[4];
#pragma unroll
        for (int mi = 0; mi < 4; ++mi)
            a[mi] = *(const short8*)(As + swz(64, wr*64 + mi*16 + (lane & 15), kk + (lane >> 4) * 8));
#pragma unroll
        for (int ni = 0; ni < 4; ++ni)
            b[ni] = *(const short8*)(Bs + swz(64, wc*64 + ni*16 + (lane & 15), kk + (lane >> 4) * 8));
#pragma unroll
        for (int mi = 0; mi < 4; ++mi)
#pragma unroll
            for (int ni = 0; ni < 4; ++ni)
                acc[mi][ni] = __builtin_amdgcn_mfma_f32_16x16x32_bf16(a[mi], b[ni], acc[mi][ni], 0, 0, 0);
    }
}

// ---------- one BK=64 MFMA step: wave computes 16 rows x 128 cols ----------
DEVINL void mfma_row16(const short* As, const short* Bs, f32x4 acc[8], int w, int lane) {
#pragma unroll
    for (int kk = 0; kk < 64; kk += 32) {
        short8 a = *(const short8*)(As + swz(64, w*16 + (lane & 15), kk + (lane >> 4) * 8));
#pragma unroll
        for (int nj = 0; nj < 8; ++nj) {
            short8 b = *(const short8*)(Bs + swz(64, nj*16 + (lane & 15), kk + (lane >> 4) * 8));
            acc[nj] = __builtin_amdgcn_mfma_f32_16x16x32_bf16(a, b, acc[nj], 0, 0, 0);
        }
    }
}

// ---------- shared 128x128 TN GEMM body (both strides 768, bf16 srcs) ----------
template<int KSTEPS>
DEVINL void gemm128_body(const short* A, const short* Bt, short* As, short* Bs,
                         f32x4 acc[4][4], int wr, int wc, int lane, int w) {
    for (int ks = 0; ks < KSTEPS; ++ks) {
        if (ks) __syncthreads();
        stage_lds_swz<128, 64>(As, A + ks * 64, DMODEL, w, lane);
        stage_lds_swz<128, 64>(Bs, Bt + ks * 64, DMODEL, w, lane);
        __syncthreads();
        mfma_step_128(As, Bs, acc, wr, wc, lane);
    }
}

// ================= kernel A: f32 -> bf16 convert (6 streams via blockIdx.z) =================
__global__ void conv_kernel(const float* q, const float* k, const float* v,
                            const float* psi, const float* omega, const float* rk,
                            short* qc, short* kc, short* vc,
                            short* psc, short* omc, short* rkc) {
    int z = blockIdx.z;
    const float* src; short* dst; int n4;     // n4 = element count / 4
    switch (z) {
        case 0: src = q;     dst = qc;  n4 = 393216; break;
        case 1: src = k;     dst = kc;  n4 = 393216; break;
        case 2: src = v;     dst = vc;  n4 = 393216; break;
        case 3: src = psi;   dst = psc; n4 = 393216; break;
        case 4: src = omega; dst = omc; n4 = 393216; break;
        default: src = rk;   dst = rkc; n4 = 147456; break;
    }
    for (int i = blockIdx.x * 256 + threadIdx.x; i < n4; i += gridDim.x * 256) {
        float4 f = *(const float4*)(src + (size_t)i * 4);
        short4 o;
        o.x = f2bf(f.x); o.y = f2bf(f.y); o.z = f2bf(f.z); o.w = f2bf(f.w);
        *(short4*)(dst + (size_t)i * 4) = o;
    }
}

// ================= kernel 0: transpose the 768x768 weights (f32 -> bf16^T) =================
__global__ void transpose_kernel(const float* wq, const float* wk, const float* wv, const float* wo,
                                 short* wqt, short* wkt, short* wvt, short* wot) {
    __shared__ float tile[64][65];
    int z = blockIdx.z;
    const float* src = (z == 0) ? wq : (z == 1) ? wk : (z == 2) ? wv : wo;
    short*       dst = (z == 0) ? wqt : (z == 1) ? wkt : (z == 2) ? wvt : wot;
    int r0 = blockIdx.x * 64, c0 = blockIdx.y * 64;
    for (int e = threadIdx.x; e < 4096; e += 256) {
        int rr = e >> 6, cc = e & 63;
        tile[rr][cc] = src[(size_t)(r0 + rr) * DMODEL + c0 + cc];
    }
    __syncthreads();
    for (int e = threadIdx.x; e < 4096; e += 256) {
        int rr = e >> 6, cc = e & 63;
        dst[(size_t)(c0 + rr) * DMODEL + r0 + cc] = f2bf(tile[cc][rr]);
    }
}

// ================= kernel 1: Q/K/V projections =================
__global__ __launch_bounds__(256, 2)
void qkv_kernel(const short* qc, const short* kc, const short* vc,
                const short* wqt, const short* wkt, const short* wvt,
                const float* bk, const float* bv, const float* rw,
                short* qw_a, short* kpack, short* vt) {
    __shared__ short As[128 * 64], Bs[128 * 64];
    int z = blockIdx.z;
    const short* A  = (z == 0) ? qc  : (z == 1) ? kc  : vc;
    const short* Bt = (z == 0) ? wqt : (z == 1) ? wkt : wvt;
    int i0 = blockIdx.x * 128, c0 = blockIdx.y * 128;
    int t = threadIdx.x, lane = t & 63, w = t >> 6, wr = w >> 1, wc = w & 1;

    f32x4 acc[4][4];
#pragma unroll
    for (int mi = 0; mi < 4; ++mi)
#pragma unroll
        for (int ni = 0; ni < 4; ++ni) acc[mi][ni] = zero4();

    gemm128_body<12>(A + (size_t)i0 * DMODEL, Bt + (size_t)c0 * DMODEL, As, Bs, acc, wr, wc, lane, w);

#pragma unroll
    for (int mi = 0; mi < 4; ++mi)
#pragma unroll
        for (int ni = 0; ni < 4; ++ni)
#pragma unroll
            for (int r = 0; r < 4; ++r) {
                int row = i0 + wr*64 + mi*16 + ((lane >> 4) << 2) + r;
                int col = c0 + wc*64 + ni*16 + (lane & 15);
                float v = acc[mi][ni][r];
                if (z == 0) {
                    qw_a[(size_t)row * DMODEL + col] = f2bf(v * SCALE + rw[col] * SCALE);
                } else if (z == 1) {
                    float vv = v + bk[col];
                    kpack[((size_t)(col >> 6) * C_LEN + row) * DHEAD + (col & 63)] = f2bf(vv);
                } else {
                    float vv = v + bv[col];
                    vt[((size_t)(col >> 6) * DHEAD + (col & 63)) * C_LEN + row] = f2bf(vv);
                }
            }
}

// ====== kernel 2: qr GEMM for a 3-head chunk; epilogue writes a1=qr*phi, a2=qr*pi ======
__global__ __launch_bounds__(256, 2)
void qr_kernel(const short* qwa, const short* rkc, const float* rr, const float* rw,
               const float* phi, const float* pi_, short* a1, short* a2, int n_base) {
    __shared__ short As[128 * 64], Bs[128 * 64];
    int nl = blockIdx.z, n = n_base + nl;
    int i0 = blockIdx.x * 128, d0 = blockIdx.y * 128;
    int t = threadIdx.x, lane = t & 63, w = t >> 6, wr = w >> 1, wc = w & 1;

    f32x4 acc[4][4];
#pragma unroll
    for (int mi = 0; mi < 4; ++mi)
#pragma unroll
        for (int ni = 0; ni < 4; ++ni) acc[mi][ni] = zero4();

    stage_addcol(As, qwa + (size_t)i0 * DMODEL + n * DHEAD, rr, rw, n * DHEAD, DMODEL);
    stage_lds_swz<128, 64>(Bs, rkc + (size_t)d0 * DMODEL + n * DHEAD, DMODEL, w, lane);
    __syncthreads();
    mfma_step_128(As, Bs, acc, wr, wc, lane);

#pragma unroll
    for (int mi = 0; mi < 4; ++mi)
#pragma unroll
        for (int ni = 0; ni < 4; ++ni)
#pragma unroll
            for (int r = 0; r < 4; ++r) {
                int row = i0 + wr*64 + mi*16 + ((lane >> 4) << 2) + r;   // i
                int col = d0 + wc*64 + ni*16 + (lane & 15);              // d
                float v = acc[mi][ni][r];
                size_t src = (size_t)row * DMODEL + col;
                size_t dst = ((size_t)nl * S_LEN + row) * DMODEL + col;
                a1[dst] = f2bf(v * phi[src]);
                a2[dst] = f2bf(v * pi_[src]);
            }
}

// ================= kernel 2b: token-type bias (qs = qwa + (rs-rw)*scale) =================
__global__ void ttb_kernel(const short* qwa, const float* seg, const float* rs, const float* rw,
                           float* ttd, float* tts) {
    int idx = blockIdx.x * 256 + threadIdx.x;       // 12*2048 total
    int n = idx >> 11, i = idx & 2047;
    const short* q  = qwa + (size_t)i * DMODEL + n * DHEAD;
    const float* e0 = seg + n * DHEAD;
    const float* e1 = seg + NHEAD * DHEAD + n * DHEAD;
    float s0 = 0.f, s1 = 0.f;
#pragma unroll
    for (int h = 0; h < DHEAD; ++h) {
        float qv = bf2f(q[h]) + (rs[n * DHEAD + h] - rw[n * DHEAD + h]) * SCALE;
        s0 += qv * e0[h];
        s1 += qv * e1[h];
    }
    ttd[n * S_LEN + i] = s0;
    tts[n * S_LEN + i] = s1;
}

// ======= kernel 3: fused score + softmax-partial + PV; 2-deep counted-vmcnt pipeline =======
// grid = 1536 1-D blocks; XCD-chunked decode with j-tile innermost for A-slab L2 reuse.
__global__ __launch_bounds__(256, 2)
void flash_kernel(const short* qw_a, const short* kpack, const short* a1, const short* a2,
                  const short* psc, const short* omc, const float* cls_mask,
                  const int* ttmat, const int* amask, const float* ttd, const float* tts,
                  const short* vt, short* pacc, float* pm, float* pl, int n_base) {
    // single LDS block: two 12288-elem pipeline buffers (As@0 Bs@4096 each), then Ps
    __shared__ short dbuf[2 * 12288];  // 48 KB
    __shared__ short Ps[64 * 128];     // 16 KB

    int orig = blockIdx.x;                       // 0..1535
    int sid  = (orig & 7) * 192 + (orig >> 3);   // XCD-chunked remap (1536 % 8 == 0, bijective)
    int jt = sid & 15;
    int q6 = sid >> 4;                           // 0..95
    int nl = q6 % 3;
    int i0 = (q6 / 3) * 64;
    int n  = n_base + nl;
    int j0 = jt * 128;

    int t = threadIdx.x, lane = t & 63, w = t >> 6;
    int lrow = lane >> 4;       // 0..3
    int lcol = lane & 15;       // 0..15

    f32x4 acc_c[8], acc_p[8];
#pragma unroll
    for (int nj = 0; nj < 8; ++nj) { acc_c[nj] = zero4(); acc_p[nj] = zero4(); }

    const short* a_base = a1 + ((size_t)nl * S_LEN + i0) * DMODEL;
    const short* a2base = a2 + ((size_t)nl * S_LEN + i0) * DMODEL;
    const short* p_base = psc + (size_t)j0 * DMODEL;
    const short* o_base = omc + (size_t)j0 * DMODEL;

    // stage step s (0..24) into buffer b (offset arithmetic keeps LDS addrspace)
    auto STAGE = [&](int b, int s) {
        short* B = dbuf + b * 12288;
        if (s == 0) {
            stage_lds_swz<64, 64>(B, qw_a + (size_t)i0 * DMODEL + n * DHEAD, DMODEL, w, lane);
            stage_lds_swz<128, 64>(B + 4096, kpack + ((size_t)n * C_LEN + j0) * DHEAD, DHEAD, w, lane);
        } else {
            int d0 = ((s - 1) % 12) * 64;
            const short* asrc = ((s <= 12) ? a_base : a2base) + d0;
            const short* bsrc = ((s <= 12) ? p_base : o_base) + d0;
            stage_lds_swz<64, 64>(B, asrc, DMODEL, w, lane);
            stage_lds_swz<128, 64>(B + 4096, bsrc, DMODEL, w, lane);
        }
    };

    // ---- prologue: 2 steps in flight (12 loads/lane outstanding) ----
    STAGE(0, 0);
    STAGE(1, 1);

    // ---- 25-step pipelined K-loop; vmcnt counted, never drained to 0 ----
    for (int ks = 0; ks < 25; ++ks) {
        int cur = ks & 1;
        short* B = dbuf + cur * 12288;
        if (ks < 24) { asm volatile("s_waitcnt vmcnt(6)" ::: "memory"); }
        else         { asm volatile("s_waitcnt vmcnt(4)" ::: "memory"); }  // only V (4 loads) younger
        __builtin_amdgcn_sched_barrier(0);
        __builtin_amdgcn_s_barrier();          // buf[cur] landed on all waves
        if (ks == 0) mfma_row16(B, B + 4096, acc_c, w, lane);
        else         mfma_row16(B, B + 4096, acc_p, w, lane);
        asm volatile("s_waitcnt lgkmcnt(0)" ::: "memory");
        __builtin_amdgcn_sched_barrier(0);
        __builtin_amdgcn_s_barrier();          // all waves done reading buf[cur]
        if (ks < 23)
            STAGE(cur, ks + 2);                // refill freed buffer, flies across 2 barriers
        else if (ks == 23)
            stage_lds_swz<64, 128>(dbuf + 12288, vt + (size_t)(n * DHEAD) * C_LEN + j0, C_LEN, w, lane);
    }

    // ---- epilogue: combine + single-tile softmax partial (V DMA in flight underneath) ----
    int iBase = i0 + w*16 + lrow*4;
    float tdiff[4], tsame[4];
#pragma unroll
    for (int r = 0; r < 4; ++r) {
        tdiff[r] = ttd[n * S_LEN + iBase + r];
        tsame[r] = tts[n * S_LEN + iBase + r];
    }
    float pbuf[8][4];
    float m[4] = { -1.0e9f, -1.0e9f, -1.0e9f, -1.0e9f };
#pragma unroll
    for (int nj = 0; nj < 8; ++nj) {
        int jg = j0 + nj*16 + lcol;
        float pen = 1.0e6f * (1.0f - (float)amask[jg]);
#pragma unroll
        for (int r = 0; r < 4; ++r) {
            size_t eidx = (size_t)(iBase + r) * C_LEN + jg;
            float clsv = cls_mask[eidx];
            float ttv  = ttmat[eidx] ? tsame[r] : tdiff[r];
            float sc = acc_c[nj][r] + clsv * (acc_p[nj][r] + ttv) - pen;
            pbuf[nj][r] = sc;
            m[r] = fmaxf(m[r], sc);
        }
    }
#pragma unroll
    for (int r = 0; r < 4; ++r) {
        float v = m[r];
        v = fmaxf(v, __shfl_xor(v, 1));
        v = fmaxf(v, __shfl_xor(v, 2));
        v = fmaxf(v, __shfl_xor(v, 4));
        v = fmaxf(v, __shfl_xor(v, 8));
        m[r] = v;
    }
    float l[4] = { 0.f, 0.f, 0.f, 0.f };
#pragma unroll
    for (int nj = 0; nj < 8; ++nj)
#pragma unroll
        for (int r = 0; r < 4; ++r) {
            float pv = __expf(fminf(pbuf[nj][r] - m[r], 0.0f));
            pbuf[nj][r] = pv;
            l[r] += pv;
        }
#pragma unroll
    for (int r = 0; r < 4; ++r) {
        float v = l[r];
        v += __shfl_xor(v, 1);
        v += __shfl_xor(v, 2);
        v += __shfl_xor(v, 4);
        v += __shfl_xor(v, 8);
        l[r] = v;
    }

    // write P tile (bf16) to LDS (swizzled; PV reads same mapping)
#pragma unroll
    for (int nj = 0; nj < 8; ++nj)
#pragma unroll
        for (int r = 0; r < 4; ++r)
            Ps[swz(128, w*16 + lrow*4 + r, nj*16 + lcol)] = f2bf(pbuf[nj][r]);

    __syncthreads();     // drains V's vmcnt + Ps lgkm; V visible to all waves

    // ---- PV (K = 128), V^T in dbuf+12288 ----
    f32x4 out_acc[4];
#pragma unroll
    for (int x = 0; x < 4; ++x) out_acc[x] = zero4();
#pragma unroll
    for (int kk = 0; kk < 4; ++kk) {
        short8 pa = *(const short8*)(Ps + swz(128, w*16 + lcol, kk*32 + lrow*8));
#pragma unroll
        for (int nh = 0; nh < 4; ++nh) {
            short8 vb = *(const short8*)(dbuf + 12288 + swz(128, nh*16 + lcol, kk*32 + lrow*8));
            out_acc[nh] = __builtin_amdgcn_mfma_f32_16x16x32_bf16(pa, vb, out_acc[nh], 0, 0, 0);
        }
    }

    // ---- write partials (unnormalized) ----
#pragma unroll
    for (int r = 0; r < 4; ++r) {
        int ig = i0 + w*16 + lrow*4 + r;
        size_t base = ((size_t)(nl * S_LEN + ig) * 16 + jt);
        if (lcol == 0) { pm[base] = m[r]; pl[base] = l[r]; }
#pragma unroll
        for (int nh = 0; nh < 4; ++nh)
            pacc[base * 64 + nh*16 + lcol] = f2bf(out_acc[nh][r]);
    }
}

// ================= kernel 3b: combine 16 j-partials -> avec =================
__global__ void combine_kernel(const short* pacc, const float* pm, const float* pl,
                               short* avec, int n_base) {
    int idx = blockIdx.x * 256 + threadIdx.x;   // 3*2048*8 threads
    int h8 = idx & 7;
    int rest = idx >> 3;
    int i  = rest & 2047;
    int nl = rest >> 11;
    size_t b = ((size_t)nl * S_LEN + i) * 16;
    float M = -1.0e30f;
#pragma unroll
    for (int p = 0; p < 16; ++p) M = fmaxf(M, pm[b + p]);
    float L = 0.f;
    float o[8] = {0.f,0.f,0.f,0.f,0.f,0.f,0.f,0.f};
#pragma unroll
    for (int p = 0; p < 16; ++p) {
        float wg = __expf(pm[b + p] - M);
        L += wg * pl[b + p];
        short8 v = *(const short8*)(pacc + (b + p) * 64 + h8 * 8);
#pragma unroll
        for (int e = 0; e < 8; ++e) o[e] += wg * bf2f(v[e]);
    }
    float invL = 1.0f / L;
    short8 r;
#pragma unroll
    for (int e = 0; e < 8; ++e) r[e] = f2bf(o[e] * invL);
    *(short8*)(avec + (size_t)i * DMODEL + (n_base + nl) * DHEAD + h8 * 8) = r;
}

// ================= kernel 4: output projection + bias + residual =================
__global__ __launch_bounds__(256, 2)
void outproj_kernel(const short* avec, const short* wot, const float* bo,
                    const float* query, float* X) {
    __shared__ short As[128 * 64], Bs[128 * 64];
    int i0 = blockIdx.x * 128, c0 = blockIdx.y * 128;
    int t = threadIdx.x, lane = t & 63, w = t >> 6, wr = w >> 1, wc = w & 1;

    f32x4 acc[4][4];
#pragma unroll
    for (int mi = 0; mi < 4; ++mi)
#pragma unroll
        for (int ni = 0; ni < 4; ++ni) acc[mi][ni] = zero4();

    gemm128_body<12>(avec + (size_t)i0 * DMODEL, wot + (size_t)c0 * DMODEL, As, Bs, acc, wr, wc, lane, w);

#pragma unroll
    for (int mi = 0; mi < 4; ++mi)
#pragma unroll
        for (int ni = 0; ni < 4; ++ni)
#pragma unroll
            for (int r = 0; r < 4; ++r) {
                int row = i0 + wr*64 + mi*16 + ((lane >> 4) << 2) + r;
                int col = c0 + wc*64 + ni*16 + (lane & 15);
                float v = acc[mi][ni][r] + bo[col];
                X[(size_t)row * DMODEL + col] = v + query[(size_t)row * DMODEL + col];
            }
}

// ================= kernel 5: layernorm (f32 in, f32 out) =================
__global__ void ln_kernel(const float* X, const float* gam, const float* bet, float* out) {
    int row = blockIdx.x, t = threadIdx.x;
    const float* xr = X + (size_t)row * DMODEL;
    float x0 = xr[t], x1 = xr[t + 256], x2 = xr[t + 512];
    float s = x0 + x1 + x2;
    float q = x0*x0 + x1*x1 + x2*x2;
#pragma unroll
    for (int d = 1; d < 64; d <<= 1) { s += __shfl_xor(s, d); q += __shfl_xor(q, d); }
    __shared__ float rs_[4], rq_[4];
    int w = t >> 6, lane = t & 63;
    if (lane == 0) { rs_[w] = s; rq_[w] = q; }
    __syncthreads();
    s = rs_[0] + rs_[1] + rs_[2] + rs_[3];
    q = rq_[0] + rq_[1] + rq_[2] + rq_[3];
    float mu  = s * (1.0f / 768.0f);
    float var = q * (1.0f / 768.0f) - mu * mu;
    float rstd = rsqrtf(fmaxf(var, 0.0f) + 1e-9f);
    out[(size_t)row * DMODEL + t]       = (x0 - mu) * rstd * gam[t]       + bet[t];
    out[(size_t)row * DMODEL + t + 256] = (x1 - mu) * rstd * gam[t + 256] + bet[t + 256];
    out[(size_t)row * DMODEL + t + 512] = (x2 - mu) * rstd * gam[t + 512] + bet[t + 512];
}

// ================= launch =================
extern "C" void kernel_launch(void* const* d_in, const int* in_sizes, int n_in,
                              void* d_out, int out_size, void* d_ws, size_t ws_size,
                              hipStream_t stream) {
    const float* query = (const float*)d_in[0];
    const float* key   = (const float*)d_in[1];
    const float* value = (const float*)d_in[2];
    const float* phi   = (const float*)d_in[3];
    const float* pi_   = (const float*)d_in[4];
    const float* psi   = (const float*)d_in[5];
    const float* omega = (const float*)d_in[6];
    const float* cls   = (const float*)d_in[7];
    const int*   ttm   = (const int*)d_in[8];
    const int*   am    = (const int*)d_in[9];
    const float* Wq    = (const float*)d_in[10];
    const float* Wk    = (const float*)d_in[11];
    const float* bk    = (const float*)d_in[12];
    const float* Wv    = (const float*)d_in[13];
    const float* bv    = (const float*)d_in[14];
    const float* rw    = (const float*)d_in[15];
    const float* rr    = (const float*)d_in[16];
    const float* rk    = (const float*)d_in[17];
    const float* rs    = (const float*)d_in[18];
    const float* seg   = (const float*)d_in[19];
    const float* Wo    = (const float*)d_in[20];
    const float* bo    = (const float*)d_in[21];
    const float* lng   = (const float*)d_in[22];
    const float* lnb   = (const float*)d_in[23];

    char* ws = (char*)d_ws;
    constexpr size_t SZ_W   = 768ull * 768 * 2;
    constexpr size_t SZ_SD  = 2048ull * 768 * 2;
    constexpr size_t SZ_3H  = 3ull * 2048 * 768 * 2;
    constexpr size_t OFF_WQT = 0;
    constexpr size_t OFF_WKT = OFF_WQT + SZ_W;
    constexpr size_t OFF_WVT = OFF_WKT + SZ_W;
    constexpr size_t OFF_WOT = OFF_WVT + SZ_W;
    constexpr size_t OFF_RKC = OFF_WOT + SZ_W;
    constexpr size_t OFF_QC  = OFF_RKC + SZ_W;
    constexpr size_t OFF_KC  = OFF_QC  + SZ_SD;
    constexpr size_t OFF_VC  = OFF_KC  + SZ_SD;
    constexpr size_t OFF_PSC = OFF_VC  + SZ_SD;
    constexpr size_t OFF_OMC = OFF_PSC + SZ_SD;
    constexpr size_t OFF_QWA = OFF_OMC + SZ_SD;
    constexpr size_t OFF_KP  = OFF_QWA + SZ_SD;
    constexpr size_t OFF_VT  = OFF_KP  + SZ_SD;
    constexpr size_t OFF_A1  = OFF_VT  + SZ_SD;
    constexpr size_t OFF_A2  = OFF_A1  + SZ_3H;
    constexpr size_t OFF_TTD = OFF_A2  + SZ_3H;
    constexpr size_t OFF_TTS = OFF_TTD + 12ull * 2048 * 4;
    constexpr size_t OFF_AV  = OFF_TTS + 12ull * 2048 * 4;
    // partial region: pacc bf16 [3][2048][16][64] + pm/pl f32 [3][2048][16]
    constexpr size_t OFF_PA  = OFF_AV  + SZ_SD;
    constexpr size_t OFF_PM  = OFF_PA  + 3ull * 2048 * 16 * 64 * 2;
    constexpr size_t OFF_PL  = OFF_PM  + 3ull * 2048 * 16 * 4;
    constexpr size_t OFF_X   = OFF_PA;                          // X aliases partials (dead by then)
    constexpr size_t NEED    = OFF_PL + 3ull * 2048 * 16 * 4;

    if (ws_size < NEED) return;   // diagnostic: leaves d_out untouched

    short* wqt  = (short*)(ws + OFF_WQT);
    short* wkt  = (short*)(ws + OFF_WKT);
    short* wvt  = (short*)(ws + OFF_WVT);
    short* wot  = (short*)(ws + OFF_WOT);
    short* rkc  = (short*)(ws + OFF_RKC);
    short* qc   = (short*)(ws + OFF_QC);
    short* kc   = (short*)(ws + OFF_KC);
    short* vc   = (short*)(ws + OFF_VC);
    short* psc  = (short*)(ws + OFF_PSC);
    short* omc  = (short*)(ws + OFF_OMC);
    short* qwa  = (short*)(ws + OFF_QWA);
    short* kp   = (short*)(ws + OFF_KP);
    short* vt   = (short*)(ws + OFF_VT);
    short* a1   = (short*)(ws + OFF_A1);
    short* a2   = (short*)(ws + OFF_A2);
    float* ttd  = (float*)(ws + OFF_TTD);
    float* tts  = (float*)(ws + OFF_TTS);
    short* avec = (short*)(ws + OFF_AV);
    short* pacc = (short*)(ws + OFF_PA);
    float* pm   = (float*)(ws + OFF_PM);
    float* pl   = (float*)(ws + OFF_PL);
    float* X    = (float*)(ws + OFF_X);

    conv_kernel<<<dim3(768, 1, 6), 256, 0, stream>>>(query, key, value, psi, omega, rk,
                                                     qc, kc, vc, psc, omc, rkc);
    transpose_kernel<<<dim3(12, 12, 4), 256, 0, stream>>>(Wq, Wk, Wv, Wo, wqt, wkt, wvt, wot);
    qkv_kernel<<<dim3(16, 6, 3), 256, 0, stream>>>(qc, kc, vc, wqt, wkt, wvt,
                                                   bk, bv, rw, qwa, kp, vt);
    ttb_kernel<<<96, 256, 0, stream>>>(qwa, seg, rs, rw, ttd, tts);
    for (int nb = 0; nb < NHEAD; nb += 3) {
        qr_kernel<<<dim3(16, 6, 3), 256, 0, stream>>>(qwa, rkc, rr, rw, phi, pi_, a1, a2, nb);
        flash_kernel<<<dim3(1536), 256, 0, stream>>>(qwa, kp, a1, a2, psc, omc, cls,
                                                     ttm, am, ttd, tts, vt, pacc, pm, pl, nb);
        combine_kernel<<<192, 256, 0, stream>>>(pacc, pm, pl, avec, nb);
    }
    outproj_kernel<<<dim3(16, 6), 256, 0, stream>>>(avec, wot, bo, query, X);
    ln_kernel<<<2048, 256, 0, stream>>>(X, lng, lnb, (float*)d_out);
}

// Round 10
// 461.332 us; speedup vs baseline: 1.1842x; 1.1842x over previous
//
#include <hip/hip_runtime.h>
#include <hip/hip_bf16.h>
#include <stddef.h>

#define DEVINL __device__ __forceinline__

typedef __attribute__((ext_vector_type(8))) short short8;
typedef __attribute__((ext_vector_type(4))) float f32x4;

static constexpr int S_LEN = 2048;
static constexpr int C_LEN = 2048;
static constexpr int DMODEL = 768;
static constexpr int NHEAD = 12;
static constexpr int DHEAD = 64;
static constexpr float SCALE = 0.125f;   // 1/sqrt(64)

// ---------- bf16 helpers (bit-level, RNE) ----------
DEVINL float bf2f(short s) {
    union { unsigned u; float f; } v;
    v.u = ((unsigned)(unsigned short)s) << 16;
    return v.f;
}
DEVINL short f2bf(float f) {
    union { float f; unsigned u; } v;
    v.f = f;
    unsigned r = v.u + 0x7FFFu + ((v.u >> 16) & 1u);
    return (short)(r >> 16);
}
DEVINL f32x4 zero4() { f32x4 z; z[0]=0.f; z[1]=0.f; z[2]=0.f; z[3]=0.f; return z; }

// ---------- LDS XOR swizzle: elem-index XOR, 16B-granule, breaks column bank aliasing ----------
DEVINL int swz(int width, int row, int col) {
    return (row * width + col) ^ ((row & 7) << 3);
}

// ---------- async global->LDS staging, width 16, source pre-swizzled (rule #21) ----------
DEVINL void gl_lds16(const short* g, short* l) {
    __builtin_amdgcn_global_load_lds(
        (const __attribute__((address_space(1))) void*)g,
        (__attribute__((address_space(3))) void*)l,
        16, 0, 0);
}

// stage [ROWS][WIDTH] bf16 tile: LDS linear dest, global src address carries the swizzle.
template<int ROWS, int WIDTH>
DEVINL void stage_lds_swz(short* lds_tile, const short* src, int src_stride, int w, int lane) {
    constexpr int CPR = WIDTH / 8;             // 16B chunks per row
    constexpr int CH  = ROWS * CPR;
    for (int c0 = w * 64; c0 < CH; c0 += 256) {
        int chunk = c0 + lane;
        int row   = chunk / CPR;
        int ccol  = chunk % CPR;
        int scol  = ccol ^ (row & 7);          // inverse swizzle on the source
        gl_lds16(src + (size_t)row * src_stride + scol * 8, lds_tile + c0 * 8);
    }
}

// ---------- VALU staging (for compute-during-stage), swizzled writes ----------
DEVINL void stage_addcol(short* dst, const short* src, const float* p1, const float* p2,
                         int col0, int src_stride) {
    for (int c = threadIdx.x; c < 1024; c += 256) {
        int row = c >> 3;
        int cc  = (c & 7) * 8;
        short8 a = *(const short8*)(src + (size_t)row * src_stride + cc);
        short8 r;
#pragma unroll
        for (int e = 0; e < 8; ++e)
            r[e] = f2bf(bf2f(a[e]) + (p1[col0 + cc + e] - p2[col0 + cc + e]) * SCALE);
        *(short8*)(dst + swz(64, row, cc)) = r;
    }
}

// ---------- one BK=64 MFMA step for a 128x128 tile, 4 waves in 2x2 of 64x64 ----------
DEVINL void mfma_step_128(const short* As, const short* Bs, f32x4 acc[4][4],
                          int wr, int wc, int lane) {
#pragma unroll
    for (int kk = 0; kk < 64; kk += 32) {
        short8 a[4], b[4];
#pragma unroll
        for (int mi = 0; mi < 4; ++mi)
            a[mi] = *(const short8*)(As + swz(64, wr*64 + mi*16 + (lane & 15), kk + (lane >> 4) * 8));
#pragma unroll
        for (int ni = 0; ni < 4; ++ni)
            b[ni] = *(const short8*)(Bs + swz(64, wc*64 + ni*16 + (lane & 15), kk + (lane >> 4) * 8));
#pragma unroll
        for (int mi = 0; mi < 4; ++mi)
#pragma unroll
            for (int ni = 0; ni < 4; ++ni)
                acc[mi][ni] = __builtin_amdgcn_mfma_f32_16x16x32_bf16(a[mi], b[ni], acc[mi][ni], 0, 0, 0);
    }
}

// ---------- 2x2-wave BK=64 step: wave (wr2,wc2) computes 32 rows x 64 cols ----------
DEVINL void mfma_2x2(const short* As, const short* Bs, f32x4 acc[2][4],
                     int wr2, int wc2, int lane) {
#pragma unroll
    for (int kk = 0; kk < 64; kk += 32) {
        short8 a[2], b[4];
#pragma unroll
        for (int mi = 0; mi < 2; ++mi)
            a[mi] = *(const short8*)(As + swz(64, wr2*32 + mi*16 + (lane & 15), kk + (lane >> 4) * 8));
#pragma unroll
        for (int nj = 0; nj < 4; ++nj)
            b[nj] = *(const short8*)(Bs + swz(64, wc2*64 + nj*16 + (lane & 15), kk + (lane >> 4) * 8));
#pragma unroll
        for (int mi = 0; mi < 2; ++mi)
#pragma unroll
            for (int nj = 0; nj < 4; ++nj)
                acc[mi][nj] = __builtin_amdgcn_mfma_f32_16x16x32_bf16(a[mi], b[nj], acc[mi][nj], 0, 0, 0);
    }
}

// ---------- shared 128x128 TN GEMM body (both strides 768, bf16 srcs) ----------
template<int KSTEPS>
DEVINL void gemm128_body(const short* A, const short* Bt, short* As, short* Bs,
                         f32x4 acc[4][4], int wr, int wc, int lane, int w) {
    for (int ks = 0; ks < KSTEPS; ++ks) {
        if (ks) __syncthreads();
        stage_lds_swz<128, 64>(As, A + ks * 64, DMODEL, w, lane);
        stage_lds_swz<128, 64>(Bs, Bt + ks * 64, DMODEL, w, lane);
        __syncthreads();
        mfma_step_128(As, Bs, acc, wr, wc, lane);
    }
}

// ============ kernel A: dtype converts (8 streams): f32->bf16, cls->bf16, ttm->int8 ============
__global__ void conv_kernel(const float* q, const float* k, const float* v,
                            const float* psi, const float* omega, const float* rk,
                            const float* cls, const int* ttm,
                            short* qc, short* kc, short* vc,
                            short* psc, short* omc, short* rkc,
                            short* clsb, char* ttm8) {
    int z = blockIdx.z;
    if (z == 7) {   // ttm int32 -> int8
        for (int i = blockIdx.x * 256 + threadIdx.x; i < 1048576; i += gridDim.x * 256) {
            int4 t = *(const int4*)(ttm + (size_t)i * 4);
            char4 o;
            o.x = (char)t.x; o.y = (char)t.y; o.z = (char)t.z; o.w = (char)t.w;
            *(char4*)(ttm8 + (size_t)i * 4) = o;
        }
        return;
    }
    const float* src; short* dst; int n4;
    switch (z) {
        case 0: src = q;     dst = qc;   n4 = 393216;  break;
        case 1: src = k;     dst = kc;   n4 = 393216;  break;
        case 2: src = v;     dst = vc;   n4 = 393216;  break;
        case 3: src = psi;   dst = psc;  n4 = 393216;  break;
        case 4: src = omega; dst = omc;  n4 = 393216;  break;
        case 5: src = rk;    dst = rkc;  n4 = 147456;  break;
        default: src = cls;  dst = clsb; n4 = 1048576; break;
    }
    for (int i = blockIdx.x * 256 + threadIdx.x; i < n4; i += gridDim.x * 256) {
        float4 f = *(const float4*)(src + (size_t)i * 4);
        short4 o;
        o.x = f2bf(f.x); o.y = f2bf(f.y); o.z = f2bf(f.z); o.w = f2bf(f.w);
        *(short4*)(dst + (size_t)i * 4) = o;
    }
}

// ================= kernel 0: transpose the 768x768 weights (f32 -> bf16^T) =================
__global__ void transpose_kernel(const float* wq, const float* wk, const float* wv, const float* wo,
                                 short* wqt, short* wkt, short* wvt, short* wot) {
    __shared__ float tile[64][65];
    int z = blockIdx.z;
    const float* src = (z == 0) ? wq : (z == 1) ? wk : (z == 2) ? wv : wo;
    short*       dst = (z == 0) ? wqt : (z == 1) ? wkt : (z == 2) ? wvt : wot;
    int r0 = blockIdx.x * 64, c0 = blockIdx.y * 64;
    for (int e = threadIdx.x; e < 4096; e += 256) {
        int rr = e >> 6, cc = e & 63;
        tile[rr][cc] = src[(size_t)(r0 + rr) * DMODEL + c0 + cc];
    }
    __syncthreads();
    for (int e = threadIdx.x; e < 4096; e += 256) {
        int rr = e >> 6, cc = e & 63;
        dst[(size_t)(c0 + rr) * DMODEL + r0 + cc] = f2bf(tile[cc][rr]);
    }
}

// ================= kernel 1: Q/K/V projections =================
__global__ __launch_bounds__(256, 2)
void qkv_kernel(const short* qc, const short* kc, const short* vc,
                const short* wqt, const short* wkt, const short* wvt,
                const float* bk, const float* bv, const float* rw,
                short* qw_a, short* kpack, short* vt) {
    __shared__ short As[128 * 64], Bs[128 * 64];
    int z = blockIdx.z;
    const short* A  = (z == 0) ? qc  : (z == 1) ? kc  : vc;
    const short* Bt = (z == 0) ? wqt : (z == 1) ? wkt : wvt;
    int i0 = blockIdx.x * 128, c0 = blockIdx.y * 128;
    int t = threadIdx.x, lane = t & 63, w = t >> 6, wr = w >> 1, wc = w & 1;

    f32x4 acc[4][4];
#pragma unroll
    for (int mi = 0; mi < 4; ++mi)
#pragma unroll
        for (int ni = 0; ni < 4; ++ni) acc[mi][ni] = zero4();

    gemm128_body<12>(A + (size_t)i0 * DMODEL, Bt + (size_t)c0 * DMODEL, As, Bs, acc, wr, wc, lane, w);

#pragma unroll
    for (int mi = 0; mi < 4; ++mi)
#pragma unroll
        for (int ni = 0; ni < 4; ++ni)
#pragma unroll
            for (int r = 0; r < 4; ++r) {
                int row = i0 + wr*64 + mi*16 + ((lane >> 4) << 2) + r;
                int col = c0 + wc*64 + ni*16 + (lane & 15);
                float v = acc[mi][ni][r];
                if (z == 0) {
                    qw_a[(size_t)row * DMODEL + col] = f2bf(v * SCALE + rw[col] * SCALE);
                } else if (z == 1) {
                    float vv = v + bk[col];
                    kpack[((size_t)(col >> 6) * C_LEN + row) * DHEAD + (col & 63)] = f2bf(vv);
                } else {
                    float vv = v + bv[col];
                    vt[((size_t)(col >> 6) * DHEAD + (col & 63)) * C_LEN + row] = f2bf(vv);
                }
            }
}

// ====== kernel 2: qr GEMM for a 3-head chunk; epilogue writes a1=qr*phi, a2=qr*pi ======
__global__ __launch_bounds__(256, 2)
void qr_kernel(const short* qwa, const short* rkc, const float* rr, const float* rw,
               const float* phi, const float* pi_, short* a1, short* a2, int n_base) {
    __shared__ short As[128 * 64], Bs[128 * 64];
    int nl = blockIdx.z, n = n_base + nl;
    int i0 = blockIdx.x * 128, d0 = blockIdx.y * 128;
    int t = threadIdx.x, lane = t & 63, w = t >> 6, wr = w >> 1, wc = w & 1;

    f32x4 acc[4][4];
#pragma unroll
    for (int mi = 0; mi < 4; ++mi)
#pragma unroll
        for (int ni = 0; ni < 4; ++ni) acc[mi][ni] = zero4();

    stage_addcol(As, qwa + (size_t)i0 * DMODEL + n * DHEAD, rr, rw, n * DHEAD, DMODEL);
    stage_lds_swz<128, 64>(Bs, rkc + (size_t)d0 * DMODEL + n * DHEAD, DMODEL, w, lane);
    __syncthreads();
    mfma_step_128(As, Bs, acc, wr, wc, lane);

#pragma unroll
    for (int mi = 0; mi < 4; ++mi)
#pragma unroll
        for (int ni = 0; ni < 4; ++ni)
#pragma unroll
            for (int r = 0; r < 4; ++r) {
                int row = i0 + wr*64 + mi*16 + ((lane >> 4) << 2) + r;   // i
                int col = d0 + wc*64 + ni*16 + (lane & 15);              // d
                float v = acc[mi][ni][r];
                size_t src = (size_t)row * DMODEL + col;
                size_t dst = ((size_t)nl * S_LEN + row) * DMODEL + col;
                a1[dst] = f2bf(v * phi[src]);
                a2[dst] = f2bf(v * pi_[src]);
            }
}

// ================= kernel 2b: token-type bias (qs = qwa + (rs-rw)*scale) =================
__global__ void ttb_kernel(const short* qwa, const float* seg, const float* rs, const float* rw,
                           float* ttd, float* tts) {
    int idx = blockIdx.x * 256 + threadIdx.x;       // 12*2048 total
    int n = idx >> 11, i = idx & 2047;
    const short* q  = qwa + (size_t)i * DMODEL + n * DHEAD;
    const float* e0 = seg + n * DHEAD;
    const float* e1 = seg + NHEAD * DHEAD + n * DHEAD;
    float s0 = 0.f, s1 = 0.f;
#pragma unroll
    for (int h = 0; h < DHEAD; ++h) {
        float qv = bf2f(q[h]) + (rs[n * DHEAD + h] - rw[n * DHEAD + h]) * SCALE;
        s0 += qv * e0[h];
        s1 += qv * e1[h];
    }
    ttd[n * S_LEN + i] = s0;
    tts[n * S_LEN + i] = s1;
}

// ======= kernel 3: fused score + softmax-partial + PV; 2-deep counted-vmcnt pipeline =======
// grid = (32, 3, 16): i0 fastest (restores R7's j-slab L2 locality). 2x2 wave split.
__global__ __launch_bounds__(256, 3)
void flash_kernel(const short* qw_a, const short* kpack, const short* a1, const short* a2,
                  const short* psc, const short* omc, const short* clsb,
                  const char* ttm8, const int* amask, const float* ttd, const float* tts,
                  const short* vt, short* pacc, float* pm, float* pl, int n_base) {
    // 48 KB total: two 12288-short pipeline buffers (As@0, Bs@4096 each).
    // Ps (8192 shorts) aliases buf0 after the K-loop (buf0 dead post-barrier).
    __shared__ short dbuf[2 * 12288];
    short* Ps = dbuf;

    int nl = blockIdx.y, n = n_base + nl;
    int i0 = blockIdx.x * 64;
    int jt = blockIdx.z;               // 0..15
    int j0 = jt * 128;

    int t = threadIdx.x, lane = t & 63, w = t >> 6;
    int wr2 = w >> 1, wc2 = w & 1;     // 2x2 wave grid: 32 rows x 64 cols each
    int lrow = lane >> 4;              // 0..3
    int lcol = lane & 15;              // 0..15

    f32x4 acc_c[2][4], acc_p[2][4];
#pragma unroll
    for (int mi = 0; mi < 2; ++mi)
#pragma unroll
        for (int nj = 0; nj < 4; ++nj) { acc_c[mi][nj] = zero4(); acc_p[mi][nj] = zero4(); }

    const short* a_base = a1 + ((size_t)nl * S_LEN + i0) * DMODEL;
    const short* a2base = a2 + ((size_t)nl * S_LEN + i0) * DMODEL;
    const short* p_base = psc + (size_t)j0 * DMODEL;
    const short* o_base = omc + (size_t)j0 * DMODEL;

    // stage step s (0..24) into buffer b; 6 loads/lane (A:2, B:4)
    auto STAGE = [&](int b, int s) {
        short* B = dbuf + b * 12288;
        if (s == 0) {
            stage_lds_swz<64, 64>(B, qw_a + (size_t)i0 * DMODEL + n * DHEAD, DMODEL, w, lane);
            stage_lds_swz<128, 64>(B + 4096, kpack + ((size_t)n * C_LEN + j0) * DHEAD, DHEAD, w, lane);
        } else {
            int d0 = ((s - 1) % 12) * 64;
            const short* asrc = ((s <= 12) ? a_base : a2base) + d0;
            const short* bsrc = ((s <= 12) ? p_base : o_base) + d0;
            stage_lds_swz<64, 64>(B, asrc, DMODEL, w, lane);
            stage_lds_swz<128, 64>(B + 4096, bsrc, DMODEL, w, lane);
        }
    };

    // ---- prologue: 2 steps in flight ----
    STAGE(0, 0);
    STAGE(1, 1);

    // ---- 25-step pipelined K-loop; vmcnt counted, never drained to 0 ----
    for (int ks = 0; ks < 25; ++ks) {
        int cur = ks & 1;
        short* B = dbuf + cur * 12288;
        if (ks < 24) { asm volatile("s_waitcnt vmcnt(6)" ::: "memory"); }
        else         { asm volatile("s_waitcnt vmcnt(4)" ::: "memory"); }  // only V (4 loads) younger
        __builtin_amdgcn_sched_barrier(0);
        __builtin_amdgcn_s_barrier();          // buf[cur] landed on all waves
        if (ks == 0) mfma_2x2(B, B + 4096, acc_c, wr2, wc2, lane);
        else         mfma_2x2(B, B + 4096, acc_p, wr2, wc2, lane);
        asm volatile("s_waitcnt lgkmcnt(0)" ::: "memory");
        __builtin_amdgcn_sched_barrier(0);
        __builtin_amdgcn_s_barrier();          // all waves done reading buf[cur]
        if (ks < 23)
            STAGE(cur, ks + 2);                // refill freed buffer, flies across 2 barriers
        else if (ks == 23)
            stage_lds_swz<64, 128>(dbuf + 12288, vt + (size_t)(n * DHEAD) * C_LEN + j0, C_LEN, w, lane);
    }

    // ---- epilogue: combine + per-64-col softmax partial (V DMA in flight underneath) ----
    float tdiff[2][4], tsame[2][4];
#pragma unroll
    for (int mi = 0; mi < 2; ++mi)
#pragma unroll
        for (int r = 0; r < 4; ++r) {
            int ig = i0 + wr2*32 + mi*16 + lrow*4 + r;
            tdiff[mi][r] = ttd[n * S_LEN + ig];
            tsame[mi][r] = tts[n * S_LEN + ig];
        }
    float pbuf[2][4][4];
    float m[2][4];
#pragma unroll
    for (int mi = 0; mi < 2; ++mi)
#pragma unroll
        for (int r = 0; r < 4; ++r) m[mi][r] = -1.0e9f;
#pragma unroll
    for (int nj = 0; nj < 4; ++nj) {
        int jg = j0 + wc2*64 + nj*16 + lcol;
        float pen = 1.0e6f * (1.0f - (float)amask[jg]);
#pragma unroll
        for (int mi = 0; mi < 2; ++mi)
#pragma unroll
            for (int r = 0; r < 4; ++r) {
                int ig = i0 + wr2*32 + mi*16 + lrow*4 + r;
                size_t eidx = (size_t)ig * C_LEN + jg;
                float clsv = bf2f(clsb[eidx]);
                float ttv  = ttm8[eidx] ? tsame[mi][r] : tdiff[mi][r];
                float sc = acc_c[mi][nj][r] + clsv * (acc_p[mi][nj][r] + ttv) - pen;
                pbuf[mi][nj][r] = sc;
                m[mi][r] = fmaxf(m[mi][r], sc);
            }
    }
#pragma unroll
    for (int mi = 0; mi < 2; ++mi)
#pragma unroll
        for (int r = 0; r < 4; ++r) {
            float v = m[mi][r];
            v = fmaxf(v, __shfl_xor(v, 1));
            v = fmaxf(v, __shfl_xor(v, 2));
            v = fmaxf(v, __shfl_xor(v, 4));
            v = fmaxf(v, __shfl_xor(v, 8));
            m[mi][r] = v;
        }
    float l[2][4];
#pragma unroll
    for (int mi = 0; mi < 2; ++mi)
#pragma unroll
        for (int r = 0; r < 4; ++r) l[mi][r] = 0.f;
#pragma unroll
    for (int nj = 0; nj < 4; ++nj)
#pragma unroll
        for (int mi = 0; mi < 2; ++mi)
#pragma unroll
            for (int r = 0; r < 4; ++r) {
                float pv = __expf(fminf(pbuf[mi][nj][r] - m[mi][r], 0.0f));
                pbuf[mi][nj][r] = pv;
                l[mi][r] += pv;
            }
#pragma unroll
    for (int mi = 0; mi < 2; ++mi)
#pragma unroll
        for (int r = 0; r < 4; ++r) {
            float v = l[mi][r];
            v += __shfl_xor(v, 1);
            v += __shfl_xor(v, 2);
            v += __shfl_xor(v, 4);
            v += __shfl_xor(v, 8);
            l[mi][r] = v;
        }

    // write P tile (bf16) to LDS (Ps aliases buf0 — safe: buf0 dead after final barrier)
#pragma unroll
    for (int mi = 0; mi < 2; ++mi)
#pragma unroll
        for (int nj = 0; nj < 4; ++nj)
#pragma unroll
            for (int r = 0; r < 4; ++r)
                Ps[swz(128, wr2*32 + mi*16 + lrow*4 + r, wc2*64 + nj*16 + lcol)] = f2bf(pbuf[mi][nj][r]);

    __syncthreads();     // drains V's vmcnt + Ps lgkm; V + P visible to all waves

    // ---- PV partial (K = 64: this wave's j-section), V^T in buf1 ----
    f32x4 out_acc[2][4];
#pragma unroll
    for (int mi = 0; mi < 2; ++mi)
#pragma unroll
        for (int nh = 0; nh < 4; ++nh) out_acc[mi][nh] = zero4();
#pragma unroll
    for (int kk = 0; kk < 2; ++kk) {
        short8 pa[2];
#pragma unroll
        for (int mi = 0; mi < 2; ++mi)
            pa[mi] = *(const short8*)(Ps + swz(128, wr2*32 + mi*16 + (lane & 15), wc2*64 + kk*32 + lrow*8));
#pragma unroll
        for (int nh = 0; nh < 4; ++nh) {
            short8 vb = *(const short8*)(dbuf + 12288 + swz(128, nh*16 + (lane & 15), wc2*64 + kk*32 + lrow*8));
#pragma unroll
            for (int mi = 0; mi < 2; ++mi)
                out_acc[mi][nh] = __builtin_amdgcn_mfma_f32_16x16x32_bf16(pa[mi], vb, out_acc[mi][nh], 0, 0, 0);
        }
    }

    // ---- write partials (unnormalized); 32 j-partials (jp = jt*2 + wc2) ----
    int jp = jt * 2 + wc2;
#pragma unroll
    for (int mi = 0; mi < 2; ++mi)
#pragma unroll
        for (int r = 0; r < 4; ++r) {
            int ig = i0 + wr2*32 + mi*16 + lrow*4 + r;
            size_t base = ((size_t)(nl * S_LEN + ig) * 32 + jp);
            if (lcol == 0) { pm[base] = m[mi][r]; pl[base] = l[mi][r]; }
#pragma unroll
            for (int nh = 0; nh < 4; ++nh)
                pacc[base * 64 + nh*16 + lcol] = f2bf(out_acc[mi][nh][r]);
        }
}

// ================= kernel 3b: combine 32 j-partials -> avec =================
__global__ void combine_kernel(const short* pacc, const float* pm, const float* pl,
                               short* avec, int n_base) {
    int idx = blockIdx.x * 256 + threadIdx.x;   // 3*2048*8 threads
    int h8 = idx & 7;
    int rest = idx >> 3;
    int i  = rest & 2047;
    int nl = rest >> 11;
    size_t b = ((size_t)nl * S_LEN + i) * 32;
    float M = -1.0e30f;
#pragma unroll
    for (int p = 0; p < 32; ++p) M = fmaxf(M, pm[b + p]);
    float L = 0.f;
    float o[8] = {0.f,0.f,0.f,0.f,0.f,0.f,0.f,0.f};
#pragma unroll
    for (int p = 0; p < 32; ++p) {
        float wg = __expf(pm[b + p] - M);
        L += wg * pl[b + p];
        short8 v = *(const short8*)(pacc + (b + p) * 64 + h8 * 8);
#pragma unroll
        for (int e = 0; e < 8; ++e) o[e] += wg * bf2f(v[e]);
    }
    float invL = 1.0f / L;
    short8 r;
#pragma unroll
    for (int e = 0; e < 8; ++e) r[e] = f2bf(o[e] * invL);
    *(short8*)(avec + (size_t)i * DMODEL + (n_base + nl) * DHEAD + h8 * 8) = r;
}

// ================= kernel 4: output projection + bias + residual =================
__global__ __launch_bounds__(256, 2)
void outproj_kernel(const short* avec, const short* wot, const float* bo,
                    const float* query, float* X) {
    __shared__ short As[128 * 64], Bs[128 * 64];
    int i0 = blockIdx.x * 128, c0 = blockIdx.y * 128;
    int t = threadIdx.x, lane = t & 63, w = t >> 6, wr = w >> 1, wc = w & 1;

    f32x4 acc[4][4];
#pragma unroll
    for (int mi = 0; mi < 4; ++mi)
#pragma unroll
        for (int ni = 0; ni < 4; ++ni) acc[mi][ni] = zero4();

    gemm128_body<12>(avec + (size_t)i0 * DMODEL, wot + (size_t)c0 * DMODEL, As, Bs, acc, wr, wc, lane, w);

#pragma unroll
    for (int mi = 0; mi < 4; ++mi)
#pragma unroll
        for (int ni = 0; ni < 4; ++ni)
#pragma unroll
            for (int r = 0; r < 4; ++r) {
                int row = i0 + wr*64 + mi*16 + ((lane >> 4) << 2) + r;
                int col = c0 + wc*64 + ni*16 + (lane & 15);
                float v = acc[mi][ni][r] + bo[col];
                X[(size_t)row * DMODEL + col] = v + query[(size_t)row * DMODEL + col];
            }
}

// ================= kernel 5: layernorm (f32 in, f32 out) =================
__global__ void ln_kernel(const float* X, const float* gam, const float* bet, float* out) {
    int row = blockIdx.x, t = threadIdx.x;
    const float* xr = X + (size_t)row * DMODEL;
    float x0 = xr[t], x1 = xr[t + 256], x2 = xr[t + 512];
    float s = x0 + x1 + x2;
    float q = x0*x0 + x1*x1 + x2*x2;
#pragma unroll
    for (int d = 1; d < 64; d <<= 1) { s += __shfl_xor(s, d); q += __shfl_xor(q, d); }
    __shared__ float rs_[4], rq_[4];
    int w = t >> 6, lane = t & 63;
    if (lane == 0) { rs_[w] = s; rq_[w] = q; }
    __syncthreads();
    s = rs_[0] + rs_[1] + rs_[2] + rs_[3];
    q = rq_[0] + rq_[1] + rq_[2] + rq_[3];
    float mu  = s * (1.0f / 768.0f);
    float var = q * (1.0f / 768.0f) - mu * mu;
    float rstd = rsqrtf(fmaxf(var, 0.0f) + 1e-9f);
    out[(size_t)row * DMODEL + t]       = (x0 - mu) * rstd * gam[t]       + bet[t];
    out[(size_t)row * DMODEL + t + 256] = (x1 - mu) * rstd * gam[t + 256] + bet[t + 256];
    out[(size_t)row * DMODEL + t + 512] = (x2 - mu) * rstd * gam[t + 512] + bet[t + 512];
}

// ================= launch =================
extern "C" void kernel_launch(void* const* d_in, const int* in_sizes, int n_in,
                              void* d_out, int out_size, void* d_ws, size_t ws_size,
                              hipStream_t stream) {
    const float* query = (const float*)d_in[0];
    const float* key   = (const float*)d_in[1];
    const float* value = (const float*)d_in[2];
    const float* phi   = (const float*)d_in[3];
    const float* pi_   = (const float*)d_in[4];
    const float* psi   = (const float*)d_in[5];
    const float* omega = (const float*)d_in[6];
    const float* cls   = (const float*)d_in[7];
    const int*   ttm   = (const int*)d_in[8];
    const int*   am    = (const int*)d_in[9];
    const float* Wq    = (const float*)d_in[10];
    const float* Wk    = (const float*)d_in[11];
    const float* bk    = (const float*)d_in[12];
    const float* Wv    = (const float*)d_in[13];
    const float* bv    = (const float*)d_in[14];
    const float* rw    = (const float*)d_in[15];
    const float* rr    = (const float*)d_in[16];
    const float* rk    = (const float*)d_in[17];
    const float* rs    = (const float*)d_in[18];
    const float* seg   = (const float*)d_in[19];
    const float* Wo    = (const float*)d_in[20];
    const float* bo    = (const float*)d_in[21];
    const float* lng   = (const float*)d_in[22];
    const float* lnb   = (const float*)d_in[23];

    char* ws = (char*)d_ws;
    constexpr size_t SZ_W   = 768ull * 768 * 2;
    constexpr size_t SZ_SD  = 2048ull * 768 * 2;
    constexpr size_t SZ_3H  = 3ull * 2048 * 768 * 2;
    constexpr size_t OFF_WQT = 0;
    constexpr size_t OFF_WKT = OFF_WQT + SZ_W;
    constexpr size_t OFF_WVT = OFF_WKT + SZ_W;
    constexpr size_t OFF_WOT = OFF_WVT + SZ_W;
    constexpr size_t OFF_RKC = OFF_WOT + SZ_W;
    constexpr size_t OFF_QC  = OFF_RKC + SZ_W;
    constexpr size_t OFF_KC  = OFF_QC  + SZ_SD;
    constexpr size_t OFF_VC  = OFF_KC  + SZ_SD;
    constexpr size_t OFF_PSC = OFF_VC  + SZ_SD;
    constexpr size_t OFF_OMC = OFF_PSC + SZ_SD;
    constexpr size_t OFF_QWA = OFF_OMC + SZ_SD;
    constexpr size_t OFF_KP  = OFF_QWA + SZ_SD;
    constexpr size_t OFF_VT  = OFF_KP  + SZ_SD;
    constexpr size_t OFF_A1  = OFF_VT  + SZ_SD;
    constexpr size_t OFF_A2  = OFF_A1  + SZ_3H;
    constexpr size_t OFF_CLB = OFF_A2  + SZ_3H;                 // cls bf16 [2048][2048]
    constexpr size_t OFF_TT8 = OFF_CLB + 2048ull * 2048 * 2;    // ttm int8
    constexpr size_t OFF_TTD = OFF_TT8 + 2048ull * 2048;
    constexpr size_t OFF_TTS = OFF_TTD + 12ull * 2048 * 4;
    constexpr size_t OFF_AV  = OFF_TTS + 12ull * 2048 * 4;
    // partial region: pacc bf16 [3][2048][32][64] + pm/pl f32 [3][2048][32]
    constexpr size_t OFF_PA  = OFF_AV  + SZ_SD;
    constexpr size_t OFF_PM  = OFF_PA  + 3ull * 2048 * 32 * 64 * 2;
    constexpr size_t OFF_PL  = OFF_PM  + 3ull * 2048 * 32 * 4;
    constexpr size_t OFF_X   = OFF_PA;                          // X aliases partials (dead by then)
    constexpr size_t NEED    = OFF_PL + 3ull * 2048 * 32 * 4;

    if (ws_size < NEED) return;   // diagnostic: leaves d_out untouched

    short* wqt  = (short*)(ws + OFF_WQT);
    short* wkt  = (short*)(ws + OFF_WKT);
    short* wvt  = (short*)(ws + OFF_WVT);
    short* wot  = (short*)(ws + OFF_WOT);
    short* rkc  = (short*)(ws + OFF_RKC);
    short* qc   = (short*)(ws + OFF_QC);
    short* kc   = (short*)(ws + OFF_KC);
    short* vc   = (short*)(ws + OFF_VC);
    short* psc  = (short*)(ws + OFF_PSC);
    short* omc  = (short*)(ws + OFF_OMC);
    short* qwa  = (short*)(ws + OFF_QWA);
    short* kp   = (short*)(ws + OFF_KP);
    short* vt   = (short*)(ws + OFF_VT);
    short* a1   = (short*)(ws + OFF_A1);
    short* a2   = (short*)(ws + OFF_A2);
    short* clsb = (short*)(ws + OFF_CLB);
    char*  ttm8 = (char*)(ws + OFF_TT8);
    float* ttd  = (float*)(ws + OFF_TTD);
    float* tts  = (float*)(ws + OFF_TTS);
    short* avec = (short*)(ws + OFF_AV);
    short* pacc = (short*)(ws + OFF_PA);
    float* pm   = (float*)(ws + OFF_PM);
    float* pl   = (float*)(ws + OFF_PL);
    float* X    = (float*)(ws + OFF_X);

    conv_kernel<<<dim3(768, 1, 8), 256, 0, stream>>>(query, key, value, psi, omega, rk, cls, ttm,
                                                     qc, kc, vc, psc, omc, rkc, clsb, ttm8);
    transpose_kernel<<<dim3(12, 12, 4), 256, 0, stream>>>(Wq, Wk, Wv, Wo, wqt, wkt, wvt, wot);
    qkv_kernel<<<dim3(16, 6, 3), 256, 0, stream>>>(qc, kc, vc, wqt, wkt, wvt,
                                                   bk, bv, rw, qwa, kp, vt);
    ttb_kernel<<<96, 256, 0, stream>>>(qwa, seg, rs, rw, ttd, tts);
    for (int nb = 0; nb < NHEAD; nb += 3) {
        qr_kernel<<<dim3(16, 6, 3), 256, 0, stream>>>(qwa, rkc, rr, rw, phi, pi_, a1, a2, nb);
        flash_kernel<<<dim3(32, 3, 16), 256, 0, stream>>>(qwa, kp, a1, a2, psc, omc, clsb,
                                                          ttm8, am, ttd, tts, vt, pacc, pm, pl, nb);
        combine_kernel<<<192, 256, 0, stream>>>(pacc, pm, pl, avec, nb);
    }
    outproj_kernel<<<dim3(16, 6), 256, 0, stream>>>(avec, wot, bo, query, X);
    ln_kernel<<<2048, 256, 0, stream>>>(X, lng, lnb, (float*)d_out);
}